// Round 9
// baseline (175.125 us; speedup 1.0000x reference)
//
#include <hip/hip_runtime.h>
#include <hip/hip_bf16.h>
#include <stddef.h>
#include <stdint.h>

typedef __bf16 bf16_t;
typedef bf16_t bf16x8 __attribute__((ext_vector_type(8)));
typedef bf16_t bf16x4 __attribute__((ext_vector_type(4)));
typedef bf16_t bf16x2 __attribute__((ext_vector_type(2)));
typedef float floatx4 __attribute__((ext_vector_type(4)));
typedef float floatx16 __attribute__((ext_vector_type(16)));
typedef int   intx4  __attribute__((ext_vector_type(4)));

#define SEQ    4096
#define DMODEL 512
#define NH     8
#define BATCH  2
#define QSCALE 0.18033688011112042f   /* 2^-3 * log2(e): folded into Q so P=exp2(S') */

// async global->LDS, 16B per lane; LDS dest = wave-uniform base + lane*16
__device__ __forceinline__ void ld_lds16(const void* g, void* l) {
  __builtin_amdgcn_global_load_lds(
      (const __attribute__((address_space(1))) unsigned int*)g,
      (__attribute__((address_space(3))) unsigned int*)l, 16, 0, 0);
}

// ---------------------------------------------------------------------------
// prep: z<4 -> Wt[z][n][k] = (bf16)W_z[k][n]; z==4 -> xb = (bf16)x
// ---------------------------------------------------------------------------
__global__ __launch_bounds__(256) void prep_k(
    const float* __restrict__ x,
    const float* __restrict__ W0, const float* __restrict__ W1,
    const float* __restrict__ W2, const float* __restrict__ W3,
    bf16_t* __restrict__ Wt, bf16_t* __restrict__ xb)
{
  if (blockIdx.z == 4) {
    const floatx4* xf = (const floatx4*)x;
    bf16x4* xo = (bf16x4*)xb;
    int base = (blockIdx.y * 16 + blockIdx.x) * 4096 + threadIdx.x;
    #pragma unroll
    for (int i = 0; i < 16; i++) {
      floatx4 v = xf[base + i * 256];
      xo[base + i * 256] = bf16x4{(bf16_t)v.x, (bf16_t)v.y, (bf16_t)v.z, (bf16_t)v.w};
    }
    return;
  }
  __shared__ float Ws[32][33];
  const float* W = (blockIdx.z == 0) ? W0 : (blockIdx.z == 1) ? W1
                 : (blockIdx.z == 2) ? W2 : W3;
  bf16_t* out = Wt + (size_t)blockIdx.z * DMODEL * DMODEL;
  const int tx = threadIdx.x & 31, ty = threadIdx.x >> 5;
  const int k0 = blockIdx.y * 32, n0 = blockIdx.x * 32;
  #pragma unroll
  for (int i = 0; i < 4; i++) {
    int kk = ty + i * 8;
    Ws[kk][tx] = W[(size_t)(k0 + kk) * DMODEL + n0 + tx];
  }
  __syncthreads();
  #pragma unroll
  for (int i = 0; i < 4; i++) {
    int nn = ty + i * 8;
    out[(size_t)(n0 + nn) * DMODEL + k0 + tx] = (bf16_t)Ws[tx][nn];
  }
}

// ---------------------------------------------------------------------------
// Fused QKV GEMM, 512 threads (8 waves -> 4 waves/SIMD at 2 blocks/CU).
// A = xb [8192x512], Wt = 3 mats [n][k]. Tile 128(M) x 32(N per matrix) x
// 64(K); one A-staging feeds 3 B-slabs. LDS/buf: A 16KB + 3x4KB B = 28KB;
// dbuf 57344 B. Wave w owns rows w*16..w*16+15.
// Epilogues: Q natural *QSCALE; K swizzled [key][d] tiles; V LDS-transpose ->
// sigma-permuted swizzled [d][tok] tiles.
// ---------------------------------------------------------------------------
__global__ __launch_bounds__(512) void qkv_k(
    const bf16_t* __restrict__ xb, const bf16_t* __restrict__ Wt,
    bf16_t* __restrict__ Qw, bf16_t* __restrict__ Ksw, bf16_t* __restrict__ Vsw)
{
  __shared__ __align__(16) char smem[2 * 1792 * 16];   // 57344 B
  const int tid  = threadIdx.x;
  const int wave = tid >> 6;          // 0..7
  const int lane = tid & 63;
  const int lh   = lane >> 4, lm = lane & 15;
  const int bm   = blockIdx.x * 128;
  const int bn   = blockIdx.y * 32;
  const int WT   = DMODEL * DMODEL;

  // A staging: 1024 16B-chunks (2/thread), XOR-swizzled source addresses
  int offA[2], ldsA[2];
  #pragma unroll
  for (int i = 0; i < 2; i++) {
    int S = i * 512 + tid;
    int r = S >> 3, cc = (S & 7) ^ (r & 7);
    offA[i] = (bm + r) * DMODEL + cc * 8;
    ldsA[i] = (i * 512 + wave * 64) * 16;
  }
  // B staging: 768 chunks (3 mats x 32 rows x 8); 1/thread + 1 for tid<256
  int offB[2], ldsB[2];
  {
    int S = tid;                       // 0..511 -> m 0..1
    int m = S >> 8, s2 = S & 255;
    int n = s2 >> 3, cc = (s2 & 7) ^ (n & 7);
    offB[0] = m * WT + (bn + n) * DMODEL + cc * 8;
    ldsB[0] = (1024 + wave * 64) * 16;
    int S1 = 512 + tid;                // m = 2 (valid for tid<256 only)
    int s21 = S1 & 255;
    int n1 = s21 >> 3, cc1 = (s21 & 7) ^ (n1 & 7);
    offB[1] = 2 * WT + (bn + n1) * DMODEL + cc1 * 8;
    ldsB[1] = (1536 + wave * 64) * 16;
  }

  floatx4 acc[3][2];
  #pragma unroll
  for (int m = 0; m < 3; m++)
    #pragma unroll
    for (int nb = 0; nb < 2; nb++) acc[m][nb] = floatx4{0.f, 0.f, 0.f, 0.f};

  auto issue = [&](int kt, int buf) {
    char* bp = smem + buf * 28672;
    ld_lds16(xb + offA[0] + kt * 64, bp + ldsA[0]);
    ld_lds16(xb + offA[1] + kt * 64, bp + ldsA[1]);
    ld_lds16(Wt + offB[0] + kt * 64, bp + ldsB[0]);
    if (tid < 256) ld_lds16(Wt + offB[1] + kt * 64, bp + ldsB[1]);
  };

  issue(0, 0);
  for (int kt = 0; kt < 8; kt++) {
    __syncthreads();                       // tile kt resident
    if (kt < 7) issue(kt + 1, (kt + 1) & 1);
    const char* bp = smem + (kt & 1) * 28672;
    int rA = wave * 16 + lm;
    #pragma unroll
    for (int ks = 0; ks < 2; ks++) {
      int cc = ks * 4 + lh;
      bf16x8 a0 = *(const bf16x8*)(bp + (rA * 8 + (cc ^ (rA & 7))) * 16);
      #pragma unroll
      for (int m = 0; m < 3; m++) {
        #pragma unroll
        for (int nb = 0; nb < 2; nb++) {
          int n = nb * 16 + lm;
          bf16x8 b = *(const bf16x8*)(bp + (1024 + m * 256 + n * 8 + (cc ^ (n & 7))) * 16);
          acc[m][nb] = __builtin_amdgcn_mfma_f32_16x16x32_bf16(a0, b, acc[m][nb], 0, 0, 0);
        }
      }
    }
  }

  const int h  = bn >> 6;           // head
  const int dl = bn & 63;           // d-offset of this 32-col slab in head
  // ---- Q: natural layout, pre-scaled ----
  #pragma unroll
  for (int nb = 0; nb < 2; nb++)
    #pragma unroll
    for (int r = 0; r < 4; r++) {
      int row = bm + wave * 16 + lh * 4 + r;
      Qw[(size_t)row * DMODEL + bn + nb * 16 + lm] = (bf16_t)(acc[0][nb][r] * QSCALE);
    }
  // ---- K: swizzled [64 key][64 d] tiles per (b,h) ----
  #pragma unroll
  for (int nb = 0; nb < 2; nb++) {
    int d = dl + nb * 16 + lm;
    #pragma unroll
    for (int r = 0; r < 4; r++) {
      int row = bm + wave * 16 + lh * 4 + r;
      int bb = row >> 12, tk = row & 4095;
      size_t off = ((size_t)(bb * NH + h) * 64 + (tk >> 6)) * 4096
                 + (size_t)(tk & 63) * 64
                 + ((((d >> 3) ^ (tk & 7)) << 3) | (d & 7));
      Ksw[off] = (bf16_t)acc[1][nb][r];
    }
  }
  // ---- V: LDS transpose -> sigma-permuted swizzled [64 d][64 tok] tiles ----
  bf16_t (*Ts)[136] = (bf16_t(*)[136])smem;   // 32 x 136 in buf0 (last read buf1)
  __syncthreads();
  #pragma unroll
  for (int nb = 0; nb < 2; nb++) {
    int dloc = nb * 16 + lm, tok0 = wave * 16 + lh * 4;
    bf16x4 v = {(bf16_t)acc[2][nb][0], (bf16_t)acc[2][nb][1],
                (bf16_t)acc[2][nb][2], (bf16_t)acc[2][nb][3]};
    *(bf16x4*)&Ts[dloc][tok0] = v;
  }
  __syncthreads();
  {
    const int bb = bm >> 12, tk0 = bm & 4095;
    const size_t hb = (size_t)(bb * NH + h) * 64;
    int idx = tid;                     // 0..511 : 32 d-rows x 16 chunks
    int dloc = idx >> 4, c8 = idx & 15;
    int d = dl + dloc;
    bf16x8 val = *(bf16x8*)&Ts[dloc][c8 * 8];
    int cw = c8 & 7;                   // chunk within 64-token tile
    int g = cw >> 1, sub = cw & 1;
    size_t tbase = (hb + (tk0 >> 6) + (c8 >> 3)) * 4096 + (size_t)d * 64;
    bf16x4 v0 = {val[0], val[1], val[2], val[3]};
    bf16x4 v1 = {val[4], val[5], val[6], val[7]};
    *(bf16x4*)&Vsw[tbase + (((2 * g) ^ (d & 7)) << 3) + sub * 4] = v0;
    *(bf16x4*)&Vsw[tbase + (((2 * g + 1) ^ (d & 7)) << 3) + sub * 4] = v1;
  }
}

// ---------------------------------------------------------------------------
// O-projection GEMM, 512 threads, tile 128x64x64, dbuf 48KB (3 blocks/CU cap,
// 4 waves/SIMD). out fp32 = Ow bf16 @ Wt3^T + bias.
// ---------------------------------------------------------------------------
__global__ __launch_bounds__(512) void out_k(
    const bf16_t* __restrict__ A, const bf16_t* __restrict__ Wt,
    const float* __restrict__ bias, float* __restrict__ out)
{
  __shared__ __align__(16) char smem[2 * 1536 * 16];   // 49152 B
  const int tid  = threadIdx.x;
  const int wave = tid >> 6;
  const int lane = tid & 63;
  const int lh   = lane >> 4, lm = lane & 15;
  const int bm   = blockIdx.x * 128;
  const int bn   = blockIdx.y * 64;

  int offA[2], ldsA[2];
  #pragma unroll
  for (int i = 0; i < 2; i++) {
    int S = i * 512 + tid;
    int r = S >> 3, cc = (S & 7) ^ (r & 7);
    offA[i] = (bm + r) * DMODEL + cc * 8;
    ldsA[i] = (i * 512 + wave * 64) * 16;
  }
  int offB, ldsOB;
  {
    int S = tid;                       // 0..511 : 64 rows x 8 chunks
    int n = S >> 3, cc = (S & 7) ^ (n & 7);
    offB  = (bn + n) * DMODEL + cc * 8;
    ldsOB = (1024 + wave * 64) * 16;
  }

  floatx4 acc[4];
  #pragma unroll
  for (int nb = 0; nb < 4; nb++) acc[nb] = floatx4{0.f, 0.f, 0.f, 0.f};

  auto issue = [&](int kt, int buf) {
    char* bp = smem + buf * 24576;
    ld_lds16(A + offA[0] + kt * 64, bp + ldsA[0]);
    ld_lds16(A + offA[1] + kt * 64, bp + ldsA[1]);
    ld_lds16(Wt + offB + kt * 64, bp + ldsOB);
  };

  issue(0, 0);
  for (int kt = 0; kt < 8; kt++) {
    __syncthreads();
    if (kt < 7) issue(kt + 1, (kt + 1) & 1);
    const char* bp = smem + (kt & 1) * 24576;
    int rA = wave * 16 + lm;
    #pragma unroll
    for (int ks = 0; ks < 2; ks++) {
      int cc = ks * 4 + lh;
      bf16x8 a0 = *(const bf16x8*)(bp + (rA * 8 + (cc ^ (rA & 7))) * 16);
      #pragma unroll
      for (int nb = 0; nb < 4; nb++) {
        int n = nb * 16 + lm;
        bf16x8 b = *(const bf16x8*)(bp + (1024 + n * 8 + (cc ^ (n & 7))) * 16);
        acc[nb] = __builtin_amdgcn_mfma_f32_16x16x32_bf16(a0, b, acc[nb], 0, 0, 0);
      }
    }
  }

  #pragma unroll
  for (int nb = 0; nb < 4; nb++) {
    float bv = bias[bn + nb * 16 + lm];
    #pragma unroll
    for (int r = 0; r < 4; r++) {
      int row = bm + wave * 16 + lh * 4 + r;
      out[(size_t)row * DMODEL + bn + nb * 16 + lm] = acc[nb][r] + bv;
    }
  }
}

// ---------------------------------------------------------------------------
// Flash attention (r7 structure) + MFMA-computed softmax denominator:
// accL = Sum_k P^T[k][q] via ones-A mfma (every C row identical), replacing
// 32 serial VALU adds + shfl per superiter.
// ---------------------------------------------------------------------------
__global__ __launch_bounds__(512, 4) void attn_k(
    const bf16_t* __restrict__ Qw, const bf16_t* __restrict__ Ksw,
    const bf16_t* __restrict__ Vsw, bf16_t* __restrict__ Ow)
{
  __shared__ __align__(16) char smem[2 * 32768];   // 64 KB
  const int tid  = threadIdx.x;
  const int wave = tid >> 6;
  const int qh   = wave >> 1;
  const int kh   = wave & 1;
  const int lane = tid & 63;
  const int hi   = lane >> 5;
  const int lo   = lane & 31;
  const int bh   = blockIdx.y, b = bh >> 3, h = bh & 7;
  const int q0   = blockIdx.x * 128;
  const size_t kvbase = (size_t)bh * 64 * 4096;

  const int qrow_g = b * SEQ + q0 + qh * 32 + lo;
  bf16x8 qreg[4];
  #pragma unroll
  for (int i = 0; i < 4; i++)
    qreg[i] = *(const bf16x8*)&Qw[(size_t)qrow_g * DMODEL + h * 64 + i * 16 + hi * 8];

  bf16x8 ones;
  #pragma unroll
  for (int i = 0; i < 8; i++) ones[i] = (bf16_t)1.0f;

  floatx16 accO[2], accL;
  #pragma unroll
  for (int nbo = 0; nbo < 2; nbo++)
    #pragma unroll
    for (int j = 0; j < 16; j++) accO[nbo][j] = 0.f;
  #pragma unroll
  for (int j = 0; j < 16; j++) accL[j] = 0.f;

  auto issue = [&](int s, int buf) {
    char* bp = smem + buf * 32768;
    const bf16_t* k0 = Ksw + kvbase + (size_t)(2 * s) * 4096;
    const bf16_t* v0 = Vsw + kvbase + (size_t)(2 * s) * 4096;
    ld_lds16(k0 + tid * 8,        bp + tid * 16);
    ld_lds16(v0 + tid * 8,        bp + 8192 + tid * 16);
    ld_lds16(k0 + 4096 + tid * 8, bp + 16384 + tid * 16);
    ld_lds16(v0 + 4096 + tid * 8, bp + 24576 + tid * 16);
  };

  issue(0, 0);
  for (int s = 0; s < SEQ / 128; s++) {
    __syncthreads();
    if (s < SEQ / 128 - 1) issue(s + 1, (s + 1) & 1);
    const bf16_t* Kb = (const bf16_t*)(smem + (s & 1) * 32768 + kh * 16384);
    const bf16_t* Vb = Kb + 4096;

    floatx16 accS[2];
    #pragma unroll
    for (int nb = 0; nb < 2; nb++)
      #pragma unroll
      for (int j = 0; j < 16; j++) accS[nb][j] = 0.f;
    #pragma unroll
    for (int kd = 0; kd < 4; kd++) {
      #pragma unroll
      for (int nb = 0; nb < 2; nb++) {
        int row = nb * 32 + lo;
        bf16x8 ak = *(const bf16x8*)&Kb[row * 64 + (((kd * 2 + hi) ^ (row & 7)) << 3)];
        accS[nb] = __builtin_amdgcn_mfma_f32_32x32x16_bf16(ak, qreg[kd], accS[nb], 0, 0, 0);
      }
    }

    int pk[2][8];
    #pragma unroll
    for (int nb = 0; nb < 2; nb++) {
      float p[16];
      #pragma unroll
      for (int r = 0; r < 16; r++) p[r] = __builtin_amdgcn_exp2f(accS[nb][r]);
      #pragma unroll
      for (int i = 0; i < 8; i++) {
        bf16x2 t2 = {(bf16_t)p[2 * i], (bf16_t)p[2 * i + 1]};
        pk[nb][i] = __builtin_bit_cast(int, t2);
      }
    }

    #pragma unroll
    for (int c = 0; c < 4; c++) {
      intx4 pi = {pk[c >> 1][4 * (c & 1)],     pk[c >> 1][4 * (c & 1) + 1],
                  pk[c >> 1][4 * (c & 1) + 2], pk[c >> 1][4 * (c & 1) + 3]};
      bf16x8 pf = __builtin_bit_cast(bf16x8, pi);
      accL = __builtin_amdgcn_mfma_f32_32x32x16_bf16(ones, pf, accL, 0, 0, 0);
      #pragma unroll
      for (int nbo = 0; nbo < 2; nbo++) {
        int row = nbo * 32 + lo;
        bf16x8 av = *(const bf16x8*)&Vb[row * 64 + (((c * 2 + hi) ^ (row & 7)) << 3)];
        accO[nbo] = __builtin_amdgcn_mfma_f32_32x32x16_bf16(av, pf, accO[nbo], 0, 0, 0);
      }
    }
  }

  // ---- merge kh pairs; padded slabs (stride 20 floats) ----
  float ls = accL[0];                  // all rows of accL identical
  __syncthreads();
  float* mrg = (float*)smem;
  if (kh == 1) {
    #pragma unroll
    for (int nbo = 0; nbo < 2; nbo++) {
      float* dst = mrg + qh * 2720 + nbo * 1360 + lane * 20;
      #pragma unroll
      for (int g = 0; g < 4; g++) {
        dst[4 * g + 0] = accO[nbo][4 * g + 0];
        dst[4 * g + 1] = accO[nbo][4 * g + 1];
        dst[4 * g + 2] = accO[nbo][4 * g + 2];
        dst[4 * g + 3] = accO[nbo][4 * g + 3];
      }
    }
    if (hi == 0) mrg[10816 + qh * 32 + lo] = ls;
  }
  __syncthreads();
  if (kh == 0) {
    float linv = 1.0f / (ls + mrg[10816 + qh * 32 + lo]);
    #pragma unroll
    for (int nbo = 0; nbo < 2; nbo++) {
      const float* src = mrg + qh * 2720 + nbo * 1360 + lane * 20;
      #pragma unroll
      for (int g = 0; g < 4; g++) {
        accO[nbo][4 * g + 0] += src[4 * g + 0];
        accO[nbo][4 * g + 1] += src[4 * g + 1];
        accO[nbo][4 * g + 2] += src[4 * g + 2];
        accO[nbo][4 * g + 3] += src[4 * g + 3];
      }
    }
    bf16_t* Os = (bf16_t*)(smem + 49152 + qh * 4096);   // [32 q][64 d]
    #pragma unroll
    for (int nbo = 0; nbo < 2; nbo++)
      #pragma unroll
      for (int g = 0; g < 4; g++) {
        int dbase = g * 8 + 4 * hi + 32 * nbo;
        bf16x4 v4 = {(bf16_t)(accO[nbo][4 * g] * linv),
                     (bf16_t)(accO[nbo][4 * g + 1] * linv),
                     (bf16_t)(accO[nbo][4 * g + 2] * linv),
                     (bf16_t)(accO[nbo][4 * g + 3] * linv)};
        *(bf16x4*)&Os[lo * 64 + (dbase ^ ((lo & 7) << 3))] = v4;
      }
    #pragma unroll
    for (int i = 0; i < 4; i++) {
      int idx = i * 64 + lane;
      int q = idx >> 3, c8 = idx & 7;
      bf16x8 v = *(const bf16x8*)&Os[q * 64 + ((c8 ^ (q & 7)) << 3)];
      int row_g = b * SEQ + q0 + qh * 32 + q;
      *(bf16x8*)&Ow[(size_t)row_g * DMODEL + h * 64 + c8 * 8] = v;
    }
  }
}

// ---------------------------------------------------------------------------
extern "C" void kernel_launch(void* const* d_in, const int* in_sizes, int n_in,
                              void* d_out, int out_size, void* d_ws, size_t ws_size,
                              hipStream_t stream)
{
  const float* x  = (const float*)d_in[0];
  const float* Wq = (const float*)d_in[1];
  const float* Wk = (const float*)d_in[2];
  const float* Wv = (const float*)d_in[3];
  const float* Wo = (const float*)d_in[4];
  const float* bo = (const float*)d_in[5];
  float* out = (float*)d_out;

  const int M = BATCH * SEQ;                     // 8192
  const size_t WT = (size_t)DMODEL * DMODEL;     // 262144
  const size_t E  = (size_t)M * DMODEL;          // 4,194,304
  if (ws_size < (4 * WT + 3 * E) * sizeof(bf16_t)) return;   // 26 MB

  bf16_t* Wt  = (bf16_t*)d_ws;
  bf16_t* Qw  = Wt + 4 * WT;
  bf16_t* Ksw = Qw + E;
  bf16_t* Vsw = Ksw + E;
  bf16_t* Ow  = Qw;             // alias: attn reads its Q rows before writing O
  bf16_t* xbf = (bf16_t*)d_out; // d_out's first 8MB as scratch: dead by out_k

  prep_k<<<dim3(16, 16, 5), 256, 0, stream>>>(x, Wq, Wk, Wv, Wo, Wt, xbf);

  qkv_k<<<dim3(M / 128, DMODEL / 32), 512, 0, stream>>>(xbf, Wt, Qw, Ksw, Vsw);

  attn_k<<<dim3(SEQ / 128, BATCH * NH), 512, 0, stream>>>(Qw, Ksw, Vsw, Ow);

  out_k<<<dim3(M / 128, DMODEL / 64), 512, 0, stream>>>(Ow, Wt + 3 * WT, bo, out);
}

// Round 10
// 173.487 us; speedup vs baseline: 1.0094x; 1.0094x over previous
//
#include <hip/hip_runtime.h>
#include <hip/hip_bf16.h>
#include <stddef.h>
#include <stdint.h>

typedef __bf16 bf16_t;
typedef bf16_t bf16x8 __attribute__((ext_vector_type(8)));
typedef bf16_t bf16x4 __attribute__((ext_vector_type(4)));
typedef bf16_t bf16x2 __attribute__((ext_vector_type(2)));
typedef float floatx4 __attribute__((ext_vector_type(4)));
typedef float floatx16 __attribute__((ext_vector_type(16)));
typedef int   intx4  __attribute__((ext_vector_type(4)));

#define SEQ    4096
#define DMODEL 512
#define NH     8
#define BATCH  2
#define QSCALE 0.18033688011112042f   /* 2^-3 * log2(e): folded into Q so P=exp2(S') */

// async global->LDS, 16B per lane; LDS dest = wave-uniform base + lane*16
__device__ __forceinline__ void ld_lds16(const void* g, void* l) {
  __builtin_amdgcn_global_load_lds(
      (const __attribute__((address_space(1))) unsigned int*)g,
      (__attribute__((address_space(3))) unsigned int*)l, 16, 0, 0);
}

// ---------------------------------------------------------------------------
// prep: z<4 -> Wt[z][n][k] = (bf16)W_z[k][n]; z==4 -> xb = (bf16)x
// ---------------------------------------------------------------------------
__global__ __launch_bounds__(256) void prep_k(
    const float* __restrict__ x,
    const float* __restrict__ W0, const float* __restrict__ W1,
    const float* __restrict__ W2, const float* __restrict__ W3,
    bf16_t* __restrict__ Wt, bf16_t* __restrict__ xb)
{
  if (blockIdx.z == 4) {
    const floatx4* xf = (const floatx4*)x;
    bf16x4* xo = (bf16x4*)xb;
    int base = (blockIdx.y * 16 + blockIdx.x) * 4096 + threadIdx.x;
    #pragma unroll
    for (int i = 0; i < 16; i++) {
      floatx4 v = xf[base + i * 256];
      xo[base + i * 256] = bf16x4{(bf16_t)v.x, (bf16_t)v.y, (bf16_t)v.z, (bf16_t)v.w};
    }
    return;
  }
  __shared__ float Ws[32][33];
  const float* W = (blockIdx.z == 0) ? W0 : (blockIdx.z == 1) ? W1
                 : (blockIdx.z == 2) ? W2 : W3;
  bf16_t* out = Wt + (size_t)blockIdx.z * DMODEL * DMODEL;
  const int tx = threadIdx.x & 31, ty = threadIdx.x >> 5;
  const int k0 = blockIdx.y * 32, n0 = blockIdx.x * 32;
  #pragma unroll
  for (int i = 0; i < 4; i++) {
    int kk = ty + i * 8;
    Ws[kk][tx] = W[(size_t)(k0 + kk) * DMODEL + n0 + tx];
  }
  __syncthreads();
  #pragma unroll
  for (int i = 0; i < 4; i++) {
    int nn = ty + i * 8;
    out[(size_t)(n0 + nn) * DMODEL + k0 + tx] = (bf16_t)Ws[tx][nn];
  }
}

// ---------------------------------------------------------------------------
// Fused QKV GEMM, 256 thr, M-grouped: block = 256 M-rows as two 128-row
// halves SHARING the B-slab (3 mats x 32 n). 16 iterations of (kt, mh):
// B loaded once per kt (halved B traffic), deeper pipeline (16 vs 8 stages).
// LDS: A dbuf 2x16KB @0, B dbuf 2x12KB @32K = 56 KB -> 2 blocks/CU.
// Epilogues: Q natural *QSCALE; K swizzled [key][d]; V LDS-transpose ->
// sigma-permuted swizzled [d][tok] tiles.
// ---------------------------------------------------------------------------
__global__ __launch_bounds__(256) void qkv_k(
    const bf16_t* __restrict__ xb, const bf16_t* __restrict__ Wt,
    bf16_t* __restrict__ Qw, bf16_t* __restrict__ Ksw, bf16_t* __restrict__ Vsw)
{
  __shared__ __align__(16) char smem[57344];   // 32K A-dbuf + 24K B-dbuf
  const int tid  = threadIdx.x;
  const int wave = tid >> 6;
  const int lane = tid & 63;
  const int lh   = lane >> 4, lm = lane & 15;
  const int bm0  = blockIdx.x * 256;
  const int bn   = blockIdx.y * 32;
  const int WTsz = DMODEL * DMODEL;

  // A staging: 1024 chunks (4/thread), XOR-swizzled source addresses
  int offAr[4], ldsA[4];
  #pragma unroll
  for (int i = 0; i < 4; i++) {
    int S = i * 256 + tid;
    int r = S >> 3, cc = (S & 7) ^ (r & 7);
    offAr[i] = r * DMODEL + cc * 8;
    ldsA[i] = (i * 256 + wave * 64) * 16;
  }
  // B staging: 768 chunks (3/thread)
  int offB[3], ldsB[3];
  #pragma unroll
  for (int j = 0; j < 3; j++) {
    int s2 = tid;                      // n-chunk within one matrix
    int n = s2 >> 3, cc = (s2 & 7) ^ (n & 7);
    offB[j] = j * WTsz + (bn + n) * DMODEL + cc * 8;
    ldsB[j] = (j * 256 + wave * 64) * 16;
  }

  floatx4 acc[2][3][2][2];             // [mh][m][rb][nb]
  #pragma unroll
  for (int mh = 0; mh < 2; mh++)
    #pragma unroll
    for (int m = 0; m < 3; m++)
      #pragma unroll
      for (int rb = 0; rb < 2; rb++)
        #pragma unroll
        for (int nb = 0; nb < 2; nb++)
          acc[mh][m][rb][nb] = floatx4{0.f, 0.f, 0.f, 0.f};

  auto issueA = [&](int it) {
    int kt = it >> 1, mh = it & 1;
    char* bp = smem + (it & 1) * 16384;
    const bf16_t* base = xb + (size_t)(bm0 + mh * 128) * DMODEL + kt * 64;
    #pragma unroll
    for (int i = 0; i < 4; i++) ld_lds16(base + offAr[i], bp + ldsA[i]);
  };
  auto issueB = [&](int kt) {
    char* bp = smem + 32768 + (kt & 1) * 12288;
    #pragma unroll
    for (int j = 0; j < 3; j++) ld_lds16(Wt + offB[j] + kt * 64, bp + ldsB[j]);
  };

  issueA(0); issueB(0);
  for (int j = 0; j < 16; j++) {
    __syncthreads();                   // stage j resident (vmcnt drained)
    if (j < 15) { issueA(j + 1); if (j & 1) issueB((j + 1) >> 1); }
    const char* bpA = smem + (j & 1) * 16384;
    const char* bpB = smem + 32768 + ((j >> 1) & 1) * 12288;
    const int mh = j & 1;
    int rA = wave * 32 + lm;
    #pragma unroll
    for (int ks = 0; ks < 2; ks++) {
      int cc = ks * 4 + lh;
      bf16x8 a0 = *(const bf16x8*)(bpA + (rA * 8 + (cc ^ (rA & 7))) * 16);
      bf16x8 a1 = *(const bf16x8*)(bpA + ((rA + 16) * 8 + (cc ^ (rA & 7))) * 16);
      #pragma unroll
      for (int m = 0; m < 3; m++) {
        #pragma unroll
        for (int nb = 0; nb < 2; nb++) {
          int n = nb * 16 + lm;
          bf16x8 b = *(const bf16x8*)(bpB + (m * 256 + n * 8 + (cc ^ (n & 7))) * 16);
          acc[mh][m][0][nb] = __builtin_amdgcn_mfma_f32_16x16x32_bf16(a0, b, acc[mh][m][0][nb], 0, 0, 0);
          acc[mh][m][1][nb] = __builtin_amdgcn_mfma_f32_16x16x32_bf16(a1, b, acc[mh][m][1][nb], 0, 0, 0);
        }
      }
    }
  }

  const int h  = bn >> 6;              // head
  const int dl = bn & 63;              // d-offset of this 32-col slab in head
  // ---- Q and K: direct stores ----
  #pragma unroll
  for (int mh = 0; mh < 2; mh++) {
    #pragma unroll
    for (int rb = 0; rb < 2; rb++)
      #pragma unroll
      for (int nb = 0; nb < 2; nb++) {
        int row = bm0 + mh * 128 + wave * 32 + rb * 16 + lh * 4;
        int d = dl + nb * 16 + lm;
        #pragma unroll
        for (int r = 0; r < 4; r++) {
          Qw[(size_t)(row + r) * DMODEL + bn + nb * 16 + lm] =
              (bf16_t)(acc[mh][0][rb][nb][r] * QSCALE);
          int rw = row + r, bb = rw >> 12, tk = rw & 4095;
          size_t off = ((size_t)(bb * NH + h) * 64 + (tk >> 6)) * 4096
                     + (size_t)(tk & 63) * 64
                     + ((((d >> 3) ^ (tk & 7)) << 3) | (d & 7));
          Ksw[off] = (bf16_t)acc[mh][1][rb][nb][r];
        }
      }
  }
  // ---- V: LDS transpose (two disjoint slabs) -> sigma-permuted tiles ----
  __syncthreads();
  #pragma unroll
  for (int mh = 0; mh < 2; mh++) {
    bf16_t (*Ts)[136] = (bf16_t(*)[136])(smem + mh * 16384);
    #pragma unroll
    for (int rb = 0; rb < 2; rb++)
      #pragma unroll
      for (int nb = 0; nb < 2; nb++) {
        int dloc = nb * 16 + lm, tok0 = wave * 32 + rb * 16 + lh * 4;
        bf16x4 v = {(bf16_t)acc[mh][2][rb][nb][0], (bf16_t)acc[mh][2][rb][nb][1],
                    (bf16_t)acc[mh][2][rb][nb][2], (bf16_t)acc[mh][2][rb][nb][3]};
        *(bf16x4*)&Ts[dloc][tok0] = v;
      }
  }
  __syncthreads();
  #pragma unroll
  for (int mh = 0; mh < 2; mh++) {
    bf16_t (*Ts)[136] = (bf16_t(*)[136])(smem + mh * 16384);
    const int bmh = bm0 + mh * 128;
    const int bb = bmh >> 12, tk0 = bmh & 4095;
    const size_t hb = (size_t)(bb * NH + h) * 64;
    #pragma unroll
    for (int i = 0; i < 2; i++) {
      int idx = tid + i * 256;         // 0..511 : 32 d-rows x 16 chunks
      int dloc = idx >> 4, c8 = idx & 15;
      int d = dl + dloc;
      bf16x8 val = *(bf16x8*)&Ts[dloc][c8 * 8];
      int cw = c8 & 7;
      int g = cw >> 1, sub = cw & 1;
      size_t tbase = (hb + (tk0 >> 6) + (c8 >> 3)) * 4096 + (size_t)d * 64;
      bf16x4 v0 = {val[0], val[1], val[2], val[3]};
      bf16x4 v1 = {val[4], val[5], val[6], val[7]};
      *(bf16x4*)&Vsw[tbase + (((2 * g) ^ (d & 7)) << 3) + sub * 4] = v0;
      *(bf16x4*)&Vsw[tbase + (((2 * g + 1) ^ (d & 7)) << 3) + sub * 4] = v1;
    }
  }
}

// ---------------------------------------------------------------------------
// O-projection GEMM (r8 version): out fp32 = Ow bf16 @ Wt3^T + bias.
// Tile 128x64x64, 256 thr, dbuf 48KB.
// ---------------------------------------------------------------------------
__global__ __launch_bounds__(256) void out_k(
    const bf16_t* __restrict__ A, const bf16_t* __restrict__ Wt,
    const float* __restrict__ bias, float* __restrict__ out)
{
  __shared__ __align__(16) char smem[2 * 1536 * 16];
  const int tid  = threadIdx.x;
  const int wave = tid >> 6;
  const int lane = tid & 63;
  const int lh   = lane >> 4, lm = lane & 15;
  const int bm   = blockIdx.x * 128;
  const int bn   = blockIdx.y * 64;

  int offA[4], ldsA[4];
  #pragma unroll
  for (int i = 0; i < 4; i++) {
    int S = i * 256 + wave * 64 + lane;
    int r = S >> 3, cc = (S & 7) ^ (r & 7);
    offA[i] = (bm + r) * DMODEL + cc * 8;
    ldsA[i] = (i * 256 + wave * 64) * 16;
  }
  int offB[2], ldsB[2];
  #pragma unroll
  for (int j = 0; j < 2; j++) {
    int S = j * 256 + wave * 64 + lane;
    int n = S >> 3, cc = (S & 7) ^ (n & 7);
    offB[j] = (bn + n) * DMODEL + cc * 8;
    ldsB[j] = (1024 + j * 256 + wave * 64) * 16;
  }

  floatx4 acc[2][4];
  #pragma unroll
  for (int rb = 0; rb < 2; rb++)
    #pragma unroll
    for (int nb = 0; nb < 4; nb++) acc[rb][nb] = floatx4{0.f, 0.f, 0.f, 0.f};

  auto issue = [&](int kt, int buf) {
    char* bp = smem + buf * 1536 * 16;
    #pragma unroll
    for (int i = 0; i < 4; i++) ld_lds16(A + offA[i] + kt * 64, bp + ldsA[i]);
    #pragma unroll
    for (int j = 0; j < 2; j++) ld_lds16(Wt + offB[j] + kt * 64, bp + ldsB[j]);
  };

  issue(0, 0);
  for (int kt = 0; kt < 8; kt++) {
    __syncthreads();
    if (kt < 7) issue(kt + 1, (kt + 1) & 1);
    const char* bp = smem + (kt & 1) * 1536 * 16;
    #pragma unroll
    for (int ks = 0; ks < 2; ks++) {
      int cc = ks * 4 + lh;
      int rA = wave * 32 + lm;
      bf16x8 a0 = *(const bf16x8*)(bp + (rA * 8 + (cc ^ (rA & 7))) * 16);
      bf16x8 a1 = *(const bf16x8*)(bp + ((rA + 16) * 8 + (cc ^ (rA & 7))) * 16);
      #pragma unroll
      for (int nb = 0; nb < 4; nb++) {
        int n = nb * 16 + lm;
        bf16x8 b = *(const bf16x8*)(bp + (1024 + n * 8 + (cc ^ (n & 7))) * 16);
        acc[0][nb] = __builtin_amdgcn_mfma_f32_16x16x32_bf16(a0, b, acc[0][nb], 0, 0, 0);
        acc[1][nb] = __builtin_amdgcn_mfma_f32_16x16x32_bf16(a1, b, acc[1][nb], 0, 0, 0);
      }
    }
  }

  #pragma unroll
  for (int rb = 0; rb < 2; rb++)
    #pragma unroll
    for (int nb = 0; nb < 4; nb++) {
      float bv = bias[bn + nb * 16 + lm];
      #pragma unroll
      for (int r = 0; r < 4; r++) {
        int row = bm + wave * 32 + rb * 16 + lh * 4 + r;
        out[(size_t)row * DMODEL + bn + nb * 16 + lm] = acc[rb][nb][r] + bv;
      }
    }
}

// ---------------------------------------------------------------------------
// Flash attention, q-tile 256: 1024 thr = 16 waves (8 qh x 2 kh). Each wave:
// 32 q, tiles of parity kh per 2-tile superiter. KV L2 traffic halves vs
// q=128. Inner loop identical to r8 (VALU denominator). Dbuf 64KB.
// Merge: two-phase (per nbo) LDS merge + per-qh transpose slabs.
// ---------------------------------------------------------------------------
__global__ __launch_bounds__(1024, 4) void attn_k(
    const bf16_t* __restrict__ Qw, const bf16_t* __restrict__ Ksw,
    const bf16_t* __restrict__ Vsw, bf16_t* __restrict__ Ow)
{
  __shared__ __align__(16) char smem[2 * 32768];   // 64 KB
  const int tid  = threadIdx.x;
  const int wave = tid >> 6;          // 0..15
  const int qh   = wave >> 1;         // 0..7
  const int kh   = wave & 1;
  const int lane = tid & 63;
  const int hi   = lane >> 5;
  const int lo   = lane & 31;
  const int bh   = blockIdx.y, b = bh >> 3, h = bh & 7;
  const int q0   = blockIdx.x * 256;
  const size_t kvbase = (size_t)bh * 64 * 4096;

  const int qrow_g = b * SEQ + q0 + qh * 32 + lo;
  bf16x8 qreg[4];
  #pragma unroll
  for (int i = 0; i < 4; i++)
    qreg[i] = *(const bf16x8*)&Qw[(size_t)qrow_g * DMODEL + h * 64 + i * 16 + hi * 8];

  floatx16 accO[2];
  #pragma unroll
  for (int nbo = 0; nbo < 2; nbo++)
    #pragma unroll
    for (int j = 0; j < 16; j++) accO[nbo][j] = 0.f;
  float ls = 0.f;

  auto issue = [&](int s, int buf) {
    char* bp = smem + buf * 32768;
    const bf16_t* k0 = Ksw + kvbase + (size_t)(2 * s) * 4096;
    const bf16_t* v0 = Vsw + kvbase + (size_t)(2 * s) * 4096;
    // layout: [K0 | V0 | K1 | V1], 8 KB each; 2 chunks per thread
    const bf16_t* sA = (tid < 512) ? (k0 + tid * 8) : (v0 + (tid - 512) * 8);
    ld_lds16(sA, bp + tid * 16);
    const bf16_t* sB = (tid < 512) ? (k0 + 4096 + tid * 8)
                                   : (v0 + 4096 + (tid - 512) * 8);
    ld_lds16(sB, bp + 16384 + tid * 16);
  };

  issue(0, 0);
  for (int s = 0; s < SEQ / 128; s++) {
    __syncthreads();
    if (s < SEQ / 128 - 1) issue(s + 1, (s + 1) & 1);
    const bf16_t* Kb = (const bf16_t*)(smem + (s & 1) * 32768 + kh * 16384);
    const bf16_t* Vb = Kb + 4096;

    floatx16 accS[2];
    #pragma unroll
    for (int nb = 0; nb < 2; nb++)
      #pragma unroll
      for (int j = 0; j < 16; j++) accS[nb][j] = 0.f;
    #pragma unroll
    for (int kd = 0; kd < 4; kd++) {
      #pragma unroll
      for (int nb = 0; nb < 2; nb++) {
        int row = nb * 32 + lo;
        bf16x8 ak = *(const bf16x8*)&Kb[row * 64 + (((kd * 2 + hi) ^ (row & 7)) << 3)];
        accS[nb] = __builtin_amdgcn_mfma_f32_32x32x16_bf16(ak, qreg[kd], accS[nb], 0, 0, 0);
      }
    }

    int pk[2][8];
    #pragma unroll
    for (int nb = 0; nb < 2; nb++) {
      float p[16];
      #pragma unroll
      for (int r = 0; r < 16; r++) p[r] = __builtin_amdgcn_exp2f(accS[nb][r]);
      #pragma unroll
      for (int r = 0; r < 16; r += 4)
        ls += (p[r] + p[r + 1]) + (p[r + 2] + p[r + 3]);
      #pragma unroll
      for (int i = 0; i < 8; i++) {
        bf16x2 t2 = {(bf16_t)p[2 * i], (bf16_t)p[2 * i + 1]};
        pk[nb][i] = __builtin_bit_cast(int, t2);
      }
    }

    #pragma unroll
    for (int c = 0; c < 4; c++) {
      intx4 pi = {pk[c >> 1][4 * (c & 1)],     pk[c >> 1][4 * (c & 1) + 1],
                  pk[c >> 1][4 * (c & 1) + 2], pk[c >> 1][4 * (c & 1) + 3]};
      bf16x8 pf = __builtin_bit_cast(bf16x8, pi);
      #pragma unroll
      for (int nbo = 0; nbo < 2; nbo++) {
        int row = nbo * 32 + lo;
        bf16x8 av = *(const bf16x8*)&Vb[row * 64 + (((c * 2 + hi) ^ (row & 7)) << 3)];
        accO[nbo] = __builtin_amdgcn_mfma_f32_32x32x16_bf16(av, pf, accO[nbo], 0, 0, 0);
      }
    }
  }

  // ---- epilogue: ls exchange, two-phase accO merge, transpose, store ----
  ls += __shfl_xor(ls, 32, 64);
  __syncthreads();                     // compute done; smem reusable
  float* lsx = (float*)smem;           // 256 floats
  if (kh == 1 && hi == 0) lsx[qh * 32 + lo] = ls;
  __syncthreads();
  float linv = 0.f;
  if (kh == 0) linv = 1.0f / (ls + lsx[qh * 32 + lo]);
  float* mrg = (float*)smem + 1024;    // 8 qh x 1360 floats = 43.5 KB
  #pragma unroll
  for (int nbo = 0; nbo < 2; nbo++) {
    __syncthreads();
    if (kh == 1) {
      float* dst = mrg + qh * 1360 + lane * 20;
      #pragma unroll
      for (int g = 0; g < 4; g++) {
        dst[4 * g + 0] = accO[nbo][4 * g + 0];
        dst[4 * g + 1] = accO[nbo][4 * g + 1];
        dst[4 * g + 2] = accO[nbo][4 * g + 2];
        dst[4 * g + 3] = accO[nbo][4 * g + 3];
      }
    }
    __syncthreads();
    if (kh == 0) {
      const float* src = mrg + qh * 1360 + lane * 20;
      #pragma unroll
      for (int g = 0; g < 4; g++) {
        accO[nbo][4 * g + 0] += src[4 * g + 0];
        accO[nbo][4 * g + 1] += src[4 * g + 1];
        accO[nbo][4 * g + 2] += src[4 * g + 2];
        accO[nbo][4 * g + 3] += src[4 * g + 3];
      }
    }
  }
  __syncthreads();                     // merge reads done; smem reusable
  if (kh == 0) {
    bf16_t* Os = (bf16_t*)(smem) + qh * 2048;   // per-qh [32 q][64 d] slab
    #pragma unroll
    for (int nbo = 0; nbo < 2; nbo++)
      #pragma unroll
      for (int g = 0; g < 4; g++) {
        int dbase = g * 8 + 4 * hi + 32 * nbo;
        bf16x4 v4 = {(bf16_t)(accO[nbo][4 * g] * linv),
                     (bf16_t)(accO[nbo][4 * g + 1] * linv),
                     (bf16_t)(accO[nbo][4 * g + 2] * linv),
                     (bf16_t)(accO[nbo][4 * g + 3] * linv)};
        *(bf16x4*)&Os[lo * 64 + (dbase ^ ((lo & 7) << 3))] = v4;
      }
    #pragma unroll
    for (int i = 0; i < 4; i++) {
      int idx = i * 64 + lane;
      int q = idx >> 3, c8 = idx & 7;
      bf16x8 v = *(const bf16x8*)&Os[q * 64 + ((c8 ^ (q & 7)) << 3)];
      int row_g = b * SEQ + q0 + qh * 32 + q;
      *(bf16x8*)&Ow[(size_t)row_g * DMODEL + h * 64 + c8 * 8] = v;
    }
  }
}

// ---------------------------------------------------------------------------
extern "C" void kernel_launch(void* const* d_in, const int* in_sizes, int n_in,
                              void* d_out, int out_size, void* d_ws, size_t ws_size,
                              hipStream_t stream)
{
  const float* x  = (const float*)d_in[0];
  const float* Wq = (const float*)d_in[1];
  const float* Wk = (const float*)d_in[2];
  const float* Wv = (const float*)d_in[3];
  const float* Wo = (const float*)d_in[4];
  const float* bo = (const float*)d_in[5];
  float* out = (float*)d_out;

  const int M = BATCH * SEQ;                     // 8192
  const size_t WT = (size_t)DMODEL * DMODEL;     // 262144
  const size_t E  = (size_t)M * DMODEL;          // 4,194,304
  if (ws_size < (4 * WT + 3 * E) * sizeof(bf16_t)) return;   // 26 MB

  bf16_t* Wt  = (bf16_t*)d_ws;
  bf16_t* Qw  = Wt + 4 * WT;
  bf16_t* Ksw = Qw + E;
  bf16_t* Vsw = Ksw + E;
  bf16_t* Ow  = Qw;             // alias: attn reads its Q rows before writing O
  bf16_t* xbf = (bf16_t*)d_out; // d_out's first 8MB as scratch: dead by out_k

  prep_k<<<dim3(16, 16, 5), 256, 0, stream>>>(x, Wq, Wk, Wv, Wo, Wt, xbf);

  qkv_k<<<dim3(M / 256, DMODEL / 32), 256, 0, stream>>>(xbf, Wt, Qw, Ksw, Vsw);

  attn_k<<<dim3(SEQ / 256, BATCH * NH), 1024, 0, stream>>>(Qw, Ksw, Vsw, Ow);

  out_k<<<dim3(M / 128, DMODEL / 64), 256, 0, stream>>>(Ow, Wt + 3 * WT, bo, out);
}